// Round 3
// baseline (19493.333 us; speedup 1.0000x reference)
//
#include <hip/hip_runtime.h>

// TimeVAEDecoder: B=128, LAT=128, H=512, F=128, L=256, NL=2
// Round 3: 3-plane bf16 split (~24 mantissa bits) for ALL GEMM operands,
// 6-MFMA products into 3 separate accumulators; two-pass LayerNorm variance
// (jnp.var semantics, no E[x^2]-m^2 cancellation); precise expf/sqrtf.
// Structure (verified by rounds 1-2 error scaling):
//  - dec eliminated via Wco = W_ihA @ W_out (s = pre+ln carries state)
//  - z_proj gate contribution precomputed into GZ0/GZ1 (fp32)
//  - ys[t] written by step t+1's phase-A extra blocks (+ epilogue t=L-1)

typedef unsigned int uint32;
typedef unsigned short u16;
typedef __attribute__((ext_vector_type(8))) short bf16x8;
typedef __attribute__((ext_vector_type(4))) float f32x4;

static constexpr int Ln = 256, Fn = 128;
static constexpr int APS = 65536;    // activation plane stride (elems): 128x512
static constexpr int WPS = 2097152;  // cell-weight plane stride: 2048x1024
static constexpr int OPS = 65536;    // W_out plane stride: 128x512
static constexpr int PPS = 262144;   // W_pre plane stride: 512x512

__device__ __forceinline__ u16 f2bf(float f) {
  union { float f; uint32 u; } v; v.f = f;
  uint32 u = v.u + 0x7fffu + ((v.u >> 16) & 1u);
  return (u16)(u >> 16);
}
__device__ __forceinline__ float bf2f(u16 h) {
  union { uint32 u; float f; } v; v.u = ((uint32)h) << 16;
  return v.f;
}
// 3-plane split: v = hi + mid + lo + O(2^-24 |v|)
__device__ __forceinline__ void splitbf3(float v, u16* hi, u16* mid, u16* lo) {
  u16 h = f2bf(v);
  float r = v - bf2f(h);
  u16 m = f2bf(r);
  float r2 = r - bf2f(m);
  *hi = h; *mid = m; *lo = f2bf(r2);
}
__device__ __forceinline__ float sigm(float x) { return 1.f / (1.f + expf(-x)); }
__device__ __forceinline__ bf16x8 ldf(const u16* p) { return *(const bf16x8*)p; }

#define MFMA1(A, B, ACC) ACC = __builtin_amdgcn_mfma_f32_16x16x32_bf16((A), (B), (ACC), 0, 0, 0)
// 6-product split accumulation: A0 += hh ; A1 += hm+mh ; A2 += hl+lh+mm
#define MFMA6(AH, AM, AL, BH, BM, BL, A0, A1, A2) \
  do {                                            \
    MFMA1(AH, BH, A0);                            \
    MFMA1(AH, BM, A1); MFMA1(AM, BH, A1);         \
    MFMA1(AH, BL, A2); MFMA1(AL, BH, A2);         \
    MFMA1(AM, BM, A2);                            \
  } while (0)

// ---------------- prep kernels ----------------

// h0/c0: (B, NL*H) row-major flat, viewed as (NL, B, H): flat = l*65536 + b'*512 + h.
__global__ void prep_hc0(const float* __restrict__ z,
                         const float* __restrict__ W_l2h, const float* __restrict__ b_l2h,
                         const float* __restrict__ W_l2c, const float* __restrict__ b_l2c,
                         u16* __restrict__ ha0, u16* __restrict__ hb0,
                         float* __restrict__ ca, float* __restrict__ cb) {
  int idx = blockIdx.x * 256 + threadIdx.x;  // 131072
  int b = idx & 127, j = idx >> 7;
  float ah = b_l2h[j], ac = b_l2c[j];
  for (int k = 0; k < 128; ++k) {
    float zv = z[b * 128 + k];
    ah += zv * W_l2h[j * 128 + k];
    ac += zv * W_l2c[j * 128 + k];
  }
  int flat = b * 1024 + j;
  if (flat < 65536) {
    splitbf3(ah, &ha0[flat], &ha0[APS + flat], &ha0[2 * APS + flat]);
    ca[flat] = ac;
  } else {
    flat -= 65536;
    splitbf3(ah, &hb0[flat], &hb0[APS + flat], &hb0[2 * APS + flat]);
    cb[flat] = ac;
  }
}

__global__ void prep_zp(const float* __restrict__ z, const float* __restrict__ W_zp,
                        const float* __restrict__ b_zp, float* __restrict__ zp) {
  int idx = blockIdx.x * 256 + threadIdx.x;  // 65536
  int b = idx & 127, h = idx >> 7;
  float a = b_zp[h];
  for (int k = 0; k < 128; ++k) a += z[b * 128 + k] * W_zp[h * 128 + k];
  zp[b * 512 + h] = a;
}

// GZ0[b][g] = zp@W_ih0[:,128:]^T + b_ih0 + b_hh0 ; GZ1 = GZ0 + b_out@W_ih0[:,:128]^T
__global__ void prep_gz(const float* __restrict__ zp, const float* __restrict__ W_ih0,
                        const float* __restrict__ b_ih0, const float* __restrict__ b_hh0,
                        const float* __restrict__ b_out,
                        float* __restrict__ GZ0, float* __restrict__ GZ1) {
  int idx = blockIdx.x * 256 + threadIdx.x;  // 262144
  int b = idx & 127, g = idx >> 7;
  const float* wr = W_ih0 + (size_t)g * 640;
  float a = b_ih0[g] + b_hh0[g];
  for (int k = 0; k < 512; ++k) a += zp[b * 512 + k] * wr[128 + k];
  float co = 0.f;
  for (int f = 0; f < 128; ++f) co += b_out[f] * wr[f];
  GZ0[b * 2048 + g] = a;
  GZ1[b * 2048 + g] = a + co;
}

// WAf[g][k]: k<512 -> Wco[g][k] = sum_f W_out[f][k]*W_ih0[g][f]; k>=512 -> W_hh0[g][k-512]
__global__ void prep_waf(const float* __restrict__ W_out, const float* __restrict__ W_ih0,
                         const float* __restrict__ W_hh0, u16* __restrict__ WAf) {
  int idx = blockIdx.x * 256 + threadIdx.x;  // 2097152
  int k = idx & 1023, g = idx >> 10;
  float v;
  if (k < 512) {
    v = 0.f;
    const float* wr = W_ih0 + (size_t)g * 640;
    for (int f = 0; f < 128; ++f) v += W_out[f * 512 + k] * wr[f];
  } else {
    v = W_hh0[(size_t)g * 512 + (k - 512)];
  }
  splitbf3(v, &WAf[idx], &WAf[WPS + idx], &WAf[2 * WPS + idx]);
}

__global__ void prep_wbf(const float* __restrict__ W_ih1, const float* __restrict__ W_hh1,
                         u16* __restrict__ WBf) {
  int idx = blockIdx.x * 256 + threadIdx.x;  // 2097152
  int k = idx & 1023, g = idx >> 10;
  float v = (k < 512) ? W_ih1[(size_t)g * 512 + k] : W_hh1[(size_t)g * 512 + (k - 512)];
  splitbf3(v, &WBf[idx], &WBf[WPS + idx], &WBf[2 * WPS + idx]);
}

__global__ void prep_misc(const float* __restrict__ W_pre, const float* __restrict__ W_out,
                          const float* __restrict__ b_ih1, const float* __restrict__ b_hh1,
                          u16* __restrict__ WPf, u16* __restrict__ WOf,
                          float* __restrict__ gb1, u16* __restrict__ s) {
  int idx = blockIdx.x * 256 + threadIdx.x;  // 526336 total
  if (idx < 262144) { splitbf3(W_pre[idx], &WPf[idx], &WPf[PPS + idx], &WPf[2 * PPS + idx]); return; }
  idx -= 262144;
  if (idx < 65536) { splitbf3(W_out[idx], &WOf[idx], &WOf[OPS + idx], &WOf[2 * OPS + idx]); return; }
  idx -= 65536;
  if (idx < 2048) { gb1[idx] = b_ih1[idx] + b_hh1[idx]; return; }
  idx -= 2048;
  if (idx < 196608) s[idx] = 0;  // all 3 planes of s: s(0)=0 -> dec(0)=0 via GZ0
}

// ---------------- per-step kernels ----------------

// LSTM cell (gate blocks) + optional ys-output blocks (phase A only).
__global__ void cell_k(const u16* __restrict__ x0, const u16* __restrict__ x1,
                       const u16* __restrict__ Wf,
                       const float* __restrict__ bias, int bias_stride,
                       float* __restrict__ cstate, u16* __restrict__ hout,
                       int n_gate_blocks,
                       const u16* sv, const u16* __restrict__ WOf,
                       const float* __restrict__ b_out, float* __restrict__ ys, int t) {
  int tid = threadIdx.x;
  int lane = tid & 63, w = tid >> 6;
  int q = lane >> 4, r16 = lane & 15;
  int blk = blockIdx.x;
  if (blk < n_gate_blocks) {
    int gg = blk & 31, bg = blk >> 5;  // gg fast -> XCD-local weight slices
    int h0 = gg * 16, b0 = bg * 16;
    const u16* wr = Wf + (size_t)(w * 512 + h0 + r16) * 1024 + q * 8;
    const u16* a0 = x0 + (size_t)(b0 + r16) * 512 + q * 8;
    const u16* a1 = x1 + (size_t)(b0 + r16) * 512 + q * 8;
    f32x4 A0 = {0.f, 0.f, 0.f, 0.f}, A1 = {0.f, 0.f, 0.f, 0.f}, A2 = {0.f, 0.f, 0.f, 0.f};
#pragma unroll
    for (int kb = 0; kb < 16; ++kb) {
      bf16x8 ah = ldf(a0 + kb * 32), am = ldf(a0 + APS + kb * 32), al = ldf(a0 + 2 * APS + kb * 32);
      bf16x8 bh = ldf(wr + kb * 32), bm = ldf(wr + WPS + kb * 32), bl = ldf(wr + 2 * WPS + kb * 32);
      MFMA6(ah, am, al, bh, bm, bl, A0, A1, A2);
    }
#pragma unroll
    for (int kb = 0; kb < 16; ++kb) {
      bf16x8 ah = ldf(a1 + kb * 32), am = ldf(a1 + APS + kb * 32), al = ldf(a1 + 2 * APS + kb * 32);
      bf16x8 bh = ldf(wr + 512 + kb * 32), bm = ldf(wr + WPS + 512 + kb * 32),
             bl = ldf(wr + 2 * WPS + 512 + kb * 32);
      MFMA6(ah, am, al, bh, bm, bl, A0, A1, A2);
    }
    __shared__ float gbuf[4][16][16];  // gate, b_loc, h_loc
#pragma unroll
    for (int r = 0; r < 4; ++r)
      gbuf[w][q * 4 + r][r16] = (A2[r] + A1[r]) + A0[r];  // small-to-large
    __syncthreads();
    int bl_ = tid >> 4, hl = tid & 15;
    int b = b0 + bl_, h = h0 + hl;
    const float* bb = bias + (size_t)b * bias_stride;  // 2048 (GZ) or 0 (gb1)
    float gi = gbuf[0][bl_][hl] + bb[h];
    float gf = gbuf[1][bl_][hl] + bb[512 + h];
    float gc = gbuf[2][bl_][hl] + bb[1024 + h];
    float go = gbuf[3][bl_][hl] + bb[1536 + h];
    int idx = b * 512 + h;
    float c = cstate[idx];
    float cn = sigm(gf) * c + sigm(gi) * tanhf(gc);
    cstate[idx] = cn;
    float hv = sigm(go) * tanhf(cn);
    splitbf3(hv, &hout[idx], &hout[APS + idx], &hout[2 * APS + idx]);
  } else {
    if (t < 1) return;  // no s yet at t=0
    int ob = blk - n_gate_blocks;  // 16 blocks: 8 bg x 2 f-halves
    int bg = ob >> 1, fh = ob & 1;
    int b0 = bg * 16, f0 = fh * 64 + w * 16;
    const u16* wr = WOf + (size_t)(f0 + r16) * 512 + q * 8;
    const u16* a = sv + (size_t)(b0 + r16) * 512 + q * 8;
    f32x4 A0 = {0.f, 0.f, 0.f, 0.f}, A1 = {0.f, 0.f, 0.f, 0.f}, A2 = {0.f, 0.f, 0.f, 0.f};
#pragma unroll
    for (int kb = 0; kb < 16; ++kb) {
      bf16x8 ah = ldf(a + kb * 32), am = ldf(a + APS + kb * 32), al = ldf(a + 2 * APS + kb * 32);
      bf16x8 bh = ldf(wr + kb * 32), bm = ldf(wr + OPS + kb * 32), bl = ldf(wr + 2 * OPS + kb * 32);
      MFMA6(ah, am, al, bh, bm, bl, A0, A1, A2);
    }
    int fc = f0 + r16;
    float bo = b_out[fc];
#pragma unroll
    for (int r = 0; r < 4; ++r) {
      int b = b0 + q * 4 + r;
      ys[(size_t)b * (Ln * Fn) + (size_t)(t - 1) * Fn + fc] = ((A2[r] + A1[r]) + A0[r]) + bo;
    }
  }
}

// LN(hb) -> pre = relu(ln@W_pre^T + b_pre) -> s = pre + ln
// Two-pass variance (jnp.var semantics), fp32 hv staged in LDS.
__global__ void lnpre_k(const u16* __restrict__ hb, const u16* __restrict__ WPf,
                        const float* __restrict__ lng, const float* __restrict__ lnb,
                        const float* __restrict__ b_pre, u16* __restrict__ s_out) {
  int tid = threadIdx.x;
  int lane = tid & 63, w = tid >> 6;
  int q = lane >> 4, r16 = lane & 15;
  int jg = blockIdx.x & 7, bg = blockIdx.x >> 3;
  int j0 = jg * 64, b0 = bg * 16;
  __shared__ float hv[16 * 516];                       // fp32 reconstructed hb tile
  __shared__ u16 lnH[16 * 520], lnM[16 * 520], lnL[16 * 520];
  __shared__ float red[16][16], smean[16], srstd[16];
  for (int i = tid; i < 16 * 512; i += 256) {
    int b = i >> 9, k = i & 511;
    size_t hidx = (size_t)(b0 + b) * 512 + k;
    hv[b * 516 + k] = (bf2f(hb[2 * APS + hidx]) + bf2f(hb[APS + hidx])) + bf2f(hb[hidx]);
  }
  __syncthreads();
  int bl_ = tid >> 4, kc = tid & 15;
  {  // pass 1: mean
    float sm = 0.f;
    for (int kk = 0; kk < 32; ++kk) sm += hv[bl_ * 516 + kc * 32 + kk];
    red[bl_][kc] = sm;
  }
  __syncthreads();
  if (tid < 16) {
    float s1 = 0.f;
    for (int i = 0; i < 16; ++i) s1 += red[tid][i];
    smean[tid] = s1 * (1.f / 512.f);
  }
  __syncthreads();
  {  // pass 2: variance of deviations (no cancellation)
    float m = smean[bl_], sq = 0.f;
    for (int kk = 0; kk < 32; ++kk) {
      float d = hv[bl_ * 516 + kc * 32 + kk] - m;
      sq += d * d;
    }
    red[bl_][kc] = sq;
  }
  __syncthreads();
  if (tid < 16) {
    float s2 = 0.f;
    for (int i = 0; i < 16; ++i) s2 += red[tid][i];
    srstd[tid] = 1.f / sqrtf(s2 * (1.f / 512.f) + 1e-5f);
  }
  __syncthreads();
  for (int i = tid; i < 16 * 512; i += 256) {
    int b = i >> 9, k = i & 511;
    float v = (hv[b * 516 + k] - smean[b]) * srstd[b] * lng[k] + lnb[k];
    splitbf3(v, &lnH[b * 520 + k], &lnM[b * 520 + k], &lnL[b * 520 + k]);
  }
  __syncthreads();
  const u16* wr = WPf + (size_t)(j0 + w * 16 + r16) * 512 + q * 8;
  const u16* aH = lnH + r16 * 520 + q * 8;
  const u16* aM = lnM + r16 * 520 + q * 8;
  const u16* aL = lnL + r16 * 520 + q * 8;
  f32x4 A0 = {0.f, 0.f, 0.f, 0.f}, A1 = {0.f, 0.f, 0.f, 0.f}, A2 = {0.f, 0.f, 0.f, 0.f};
#pragma unroll
  for (int kb = 0; kb < 16; ++kb) {
    bf16x8 ah = ldf(aH + kb * 32), am = ldf(aM + kb * 32), al = ldf(aL + kb * 32);
    bf16x8 bh = ldf(wr + kb * 32), bm = ldf(wr + PPS + kb * 32), bl = ldf(wr + 2 * PPS + kb * 32);
    MFMA6(ah, am, al, bh, bm, bl, A0, A1, A2);
  }
  int j = j0 + w * 16 + r16;
  float bp = b_pre[j];
#pragma unroll
  for (int r = 0; r < 4; ++r) {
    int b = q * 4 + r;
    float lnv = (hv[b * 516 + j] - smean[b]) * srstd[b] * lng[j] + lnb[j];  // exact fp32 recompute
    float pre = fmaxf(((A2[r] + A1[r]) + A0[r]) + bp, 0.f);
    float sval = pre + lnv;
    size_t sidx = (size_t)(b0 + b) * 512 + j;
    splitbf3(sval, &s_out[sidx], &s_out[APS + sidx], &s_out[2 * APS + sidx]);
  }
}

// ---------------- host ----------------

extern "C" void kernel_launch(void* const* d_in, const int* in_sizes, int n_in,
                              void* d_out, int out_size, void* d_ws, size_t ws_size,
                              hipStream_t stream) {
  const float* z     = (const float*)d_in[0];
  const float* W_l2h = (const float*)d_in[1];
  const float* b_l2h = (const float*)d_in[2];
  const float* W_l2c = (const float*)d_in[3];
  const float* b_l2c = (const float*)d_in[4];
  const float* W_zp  = (const float*)d_in[5];
  const float* b_zp  = (const float*)d_in[6];
  const float* W_ih0 = (const float*)d_in[7];
  const float* W_hh0 = (const float*)d_in[8];
  const float* b_ih0 = (const float*)d_in[9];
  const float* b_hh0 = (const float*)d_in[10];
  const float* W_ih1 = (const float*)d_in[11];
  const float* W_hh1 = (const float*)d_in[12];
  const float* b_ih1 = (const float*)d_in[13];
  const float* b_hh1 = (const float*)d_in[14];
  const float* ln_g  = (const float*)d_in[15];
  const float* ln_b  = (const float*)d_in[16];
  const float* W_pre = (const float*)d_in[17];
  const float* b_pre = (const float*)d_in[18];
  const float* W_out = (const float*)d_in[19];
  const float* b_out = (const float*)d_in[20];
  float* out = (float*)d_out;
  char* ws = (char*)d_ws;

  size_t off = 0;
  auto alloc = [&](size_t bytes) { void* p = ws + off; off += bytes; return p; };
  u16*   WAf  = (u16*)alloc(12582912);   // 3 planes x 2048x1024 bf16
  u16*   WBf  = (u16*)alloc(12582912);
  u16*   WPf  = (u16*)alloc(1572864);    // 3 x 512x512
  u16*   WOf  = (u16*)alloc(393216);     // 3 x 128x512
  float* GZ0  = (float*)alloc(1048576);
  float* GZ1  = (float*)alloc(1048576);
  float* gb1  = (float*)alloc(8192);
  float* zp   = (float*)alloc(262144);
  u16*   ha[2], *hbuf[2];
  ha[0]   = (u16*)alloc(393216);         // 3 planes x 128x512
  ha[1]   = (u16*)alloc(393216);
  hbuf[0] = (u16*)alloc(393216);
  hbuf[1] = (u16*)alloc(393216);
  float* ca   = (float*)alloc(262144);
  float* cb   = (float*)alloc(262144);
  u16*   sbuf = (u16*)alloc(393216);

  prep_hc0<<<512, 256, 0, stream>>>(z, W_l2h, b_l2h, W_l2c, b_l2c, ha[0], hbuf[0], ca, cb);
  prep_zp<<<256, 256, 0, stream>>>(z, W_zp, b_zp, zp);
  prep_gz<<<1024, 256, 0, stream>>>(zp, W_ih0, b_ih0, b_hh0, b_out, GZ0, GZ1);
  prep_waf<<<8192, 256, 0, stream>>>(W_out, W_ih0, W_hh0, WAf);
  prep_wbf<<<8192, 256, 0, stream>>>(W_ih1, W_hh1, WBf);
  prep_misc<<<2056, 256, 0, stream>>>(W_pre, W_out, b_ih1, b_hh1, WPf, WOf, gb1, sbuf);

  for (int t = 0; t < Ln; ++t) {
    // phase A: cell0 (K=1024: s||ha) + 16 extra blocks writing ys[t-1]
    cell_k<<<272, 256, 0, stream>>>(sbuf, ha[t & 1], WAf, t ? GZ1 : GZ0, 2048,
                                    ca, ha[(t + 1) & 1], 256, sbuf, WOf, b_out, out, t);
    // phase B: cell1 (K=1024: ha'||hb)
    cell_k<<<256, 256, 0, stream>>>(ha[(t + 1) & 1], hbuf[t & 1], WBf, gb1, 0,
                                    cb, hbuf[(t + 1) & 1], 256, sbuf, WOf, b_out, out, 0);
    // phase C: layernorm + pre + s'
    lnpre_k<<<64, 256, 0, stream>>>(hbuf[(t + 1) & 1], WPf, ln_g, ln_b, b_pre, sbuf);
  }
  // epilogue: ys[L-1] from final s
  cell_k<<<16, 256, 0, stream>>>(sbuf, ha[0], WAf, GZ1, 2048, ca, ha[1],
                                 0, sbuf, WOf, b_out, out, Ln);
}